// Round 5
// baseline (102.815 us; speedup 1.0000x reference)
//
#include <hip/hip_runtime.h>
#include <hip/hip_bf16.h>

// Chamfer, B=4, N=M=8192 fp32 -> scalar. Round 5: packed fp32 (v_pk_fma_f32).
// Evidence: rounds 1/3/4 all sustain ~3.9 cyc per designed VALU wave-instr at VALUBusy~100%
// -> fp32 FMA issue is the wall. pk_fma does 2 fp32 FMA per instr: pair q-points into
// packed lanes -> 3 pk_fma + 1 v_min3 per 2 pairs = 2.0 instr/pair (was 3.5).
// LDS holds q premultiplied (-2x,-2y,-2z,|q|^2) in SoA component arrays so one broadcast
// ds_read_b128 yields 4 q's worth of one component = two float2 operands (free aliasing).
// p splatted to float2 once (loop-invariant, deterministic; no op_sel reliance).

#define BATCH 4
#define NPTS 8192
#define MS 32                  // m-chunks per direction
#define RPT 8                  // n-points per thread
#define CHUNK (NPTS / MS)      // 256 q-points per block
#define SETPTS (BATCH * NPTS)  // 32768

typedef float v2f __attribute__((ext_vector_type(2)));

__global__ __launch_bounds__(256, 4) void chamfer_min_kernel(
    const float* __restrict__ p1, const float* __restrict__ p2,
    unsigned int* __restrict__ wmin) {
  const int mchunk = blockIdx.x;  // 0..MS-1
  const int nblk = blockIdx.y;    // 0..3
  const int zb = blockIdx.z;      // 0..7
  const int dir = zb >> 2;        // 0: P=p1,Q=p2 ; 1: P=p2,Q=p1
  const int b = zb & 3;
  const float* __restrict__ P = (dir ? p2 : p1) + (size_t)b * NPTS * 3;
  const float* __restrict__ Q = (dir ? p1 : p2) + (size_t)b * NPTS * 3;
  unsigned int* __restrict__ wm = wmin + ((size_t)dir * BATCH + b) * NPTS;

  const int t = threadIdx.x;

  // SoA component arrays: one ds_read_b128 = one component of 4 consecutive q
  __shared__ float4 sx4[CHUNK / 4], sy4[CHUNK / 4], sz4[CHUNK / 4], sw4[CHUNK / 4];
  {
    const float* qp = Q + (size_t)(mchunk * CHUNK + t) * 3;
    const float x = qp[0], y = qp[1], z = qp[2];
    ((float*)sx4)[t] = -2.f * x;
    ((float*)sy4)[t] = -2.f * y;
    ((float*)sz4)[t] = -2.f * z;
    ((float*)sw4)[t] = fmaf(x, x, fmaf(y, y, z * z));
  }

  // p points: raw coords splatted into float2 (loop-invariant pk_fma operands)
  v2f PX[RPT], PY[RPT], PZ[RPT];
  float acc[RPT];
#pragma unroll
  for (int r = 0; r < RPT; ++r) {
    const int n = nblk * (RPT * 256) + r * 256 + t;
    const float* pp = P + (size_t)n * 3;
    PX[r] = (v2f){pp[0], pp[0]};
    PY[r] = (v2f){pp[1], pp[1]};
    PZ[r] = (v2f){pp[2], pp[2]};
    acc[r] = INFINITY;  // min over q of (|q|^2 - 2 p.q)
  }
  __syncthreads();

  for (int k = 0; k < CHUNK / 4; ++k) {
    const float4 X = sx4[k];  // broadcast ds_read_b128: x of q[4k..4k+3]
    const float4 Y = sy4[k];
    const float4 Z = sz4[k];
    const float4 W = sw4[k];
    const v2f xa = {X.x, X.y}, xb = {X.z, X.w};
    const v2f ya = {Y.x, Y.y}, yb = {Y.z, Y.w};
    const v2f za = {Z.x, Z.y}, zb2 = {Z.z, Z.w};
    const v2f wa = {W.x, W.y}, wb = {W.z, W.w};
#pragma unroll
    for (int r = 0; r < RPT; ++r) {
      const v2f ca = __builtin_elementwise_fma(
          PX[r], xa, __builtin_elementwise_fma(PY[r], ya,
                         __builtin_elementwise_fma(PZ[r], za, wa)));
      const v2f cb = __builtin_elementwise_fma(
          PX[r], xb, __builtin_elementwise_fma(PY[r], yb,
                         __builtin_elementwise_fma(PZ[r], zb2, wb)));
      acc[r] = fminf(acc[r], fminf(ca.x, ca.y));  // v_min3_f32
      acc[r] = fminf(acc[r], fminf(cb.x, cb.y));  // v_min3_f32
    }
  }

#pragma unroll
  for (int r = 0; r < RPT; ++r) {
    const int n = nblk * (RPT * 256) + r * 256 + t;
    const float px = PX[r].x, py = PY[r].x, pz = PZ[r].x;
    const float pw = fmaf(px, px, fmaf(py, py, pz * pz));
    const float v = fmaxf(acc[r] + pw, 0.f);  // clamp keeps uint-ordered atomicMin valid
    atomicMin(&wm[n], __float_as_uint(v));
  }
}

__global__ __launch_bounds__(1024) void chamfer_reduce_kernel(
    const float4* __restrict__ wmin4, float* __restrict__ out) {
  // 65536 floats = 16384 float4; one block of 1024 threads, 16 float4 each
  float s = 0.f;
  const int t = threadIdx.x;
#pragma unroll
  for (int k = 0; k < 16; ++k) {
    const float4 v = wmin4[k * 1024 + t];
    s += (v.x + v.y) + (v.z + v.w);
  }
#pragma unroll
  for (int off = 32; off > 0; off >>= 1) s += __shfl_down(s, off, 64);
  __shared__ float wsum[16];
  const int lane = t & 63, wid = t >> 6;
  if (lane == 0) wsum[wid] = s;
  __syncthreads();
  if (t == 0) {
    float tot = 0.f;
#pragma unroll
    for (int w = 0; w < 16; ++w) tot += wsum[w];
    out[0] = tot;
  }
}

extern "C" void kernel_launch(void* const* d_in, const int* in_sizes, int n_in,
                              void* d_out, int out_size, void* d_ws, size_t ws_size,
                              hipStream_t stream) {
  const float* p1 = (const float*)d_in[0];
  const float* p2 = (const float*)d_in[1];
  float* out = (float*)d_out;
  unsigned int* wmin = (unsigned int*)d_ws;  // 2*SETPTS u32 = 256 KB

  // uint-ordered +inf: every clamped (>=0) float bit pattern is < 0xFFFFFFFF
  hipMemsetAsync(wmin, 0xFF, 2 * SETPTS * sizeof(unsigned int), stream);

  dim3 grid(MS, NPTS / (RPT * 256), 2 * BATCH);
  chamfer_min_kernel<<<grid, dim3(256), 0, stream>>>(p1, p2, wmin);

  chamfer_reduce_kernel<<<dim3(1), dim3(1024), 0, stream>>>((const float4*)wmin, out);
}